// Round 12
// baseline (389.157 us; speedup 1.0000x reference)
//
#include <hip/hip_runtime.h>

typedef unsigned short u16;
typedef unsigned int u32;
typedef __bf16 bf16x8 __attribute__((ext_vector_type(8)));
typedef float f32x4 __attribute__((ext_vector_type(4)));
typedef u16 u16x8 __attribute__((ext_vector_type(8)));

#define IN_CH 256
#define HID 64
#define BSHIFT 7            // 128 nodes per bucket
#define BNODES 128
#define NBUK 782            // ceil(100000 / 128)
#define BCAP 5632           // mean 4092 edges/bucket; +24 sigma headroom
#define TILE 8192           // edges per partition tile

__device__ __forceinline__ u16 f2bf(float f) {
  union { float f; unsigned u; } v; v.f = f;
  unsigned r = v.u + 0x7FFFu + ((v.u >> 16) & 1u);  // RNE
  return (u16)(r >> 16);
}
__device__ __forceinline__ float bf2f(u16 h) {
  union { unsigned u; float f; } v; v.u = ((unsigned)h) << 16;
  return v.f;
}

// W1 + W2 transpose to bf16 [n][k] layouts, AND zero bcnt (absorbed memset).
__global__ void k_wprep(const float* __restrict__ W1, const float* __restrict__ W2,
                        u16* __restrict__ w1t, u16* __restrict__ w2t,
                        int* __restrict__ bcnt) {
  int t = blockIdx.x * blockDim.x + threadIdx.x;
  if (t < 64 * 256) {
    int n = t >> 8, k = t & 255;
    w1t[t] = f2bf(W1[k * 64 + n]);
  }
  int t2 = t - 64 * 256;
  if (t2 >= 0 && t2 < 64 * 64) {
    int n = t2 >> 6, k = t2 & 63;
    w2t[t2] = f2bf(W2[k * 64 + n]);
  }
  if (t < NBUK) bcnt[t] = 0;
}

// ---------------- phase A: LDS-staged bucket partition (128-node buckets) ----------------
// Edge packed as u32: src (bits 0-19) | dloc (bits 20-26). Proven in round 8.

__global__ __launch_bounds__(1024) void k_part(const int* __restrict__ e_src,
                                               const int* __restrict__ e_dst,
                                               int* __restrict__ bcnt,
                                               u32* __restrict__ bedge, int E) {
  __shared__ int lcnt[1024];
  __shared__ int lscan[1024];
  __shared__ int gbase[1024];
  __shared__ int wsum[16];
  __shared__ u32 stag[TILE];
  __shared__ int dest[TILE];
  int t = threadIdx.x;
  int base = blockIdx.x * TILE;
  int here = E - base; if (here > TILE) here = TILE;

  lcnt[t] = 0;
  __syncthreads();

  u32 m[8]; int bk[8]; int rk[8];
#pragma unroll
  for (int k = 0; k < 8; ++k) {
    int e = base + t + k * 1024;
    if (e < E) {
      int s = e_src[e], d = e_dst[e];
      bk[k] = d >> BSHIFT;
      m[k] = (u32)s | ((u32)(d & (BNODES - 1)) << 20);
      rk[k] = atomicAdd(&lcnt[bk[k]], 1);
    } else bk[k] = -1;
  }
  __syncthreads();

  // exclusive scan of lcnt[0..1023] (16 waves)
  int lane = t & 63, w = t >> 6;
  int v = lcnt[t], x = v;
#pragma unroll
  for (int off = 1; off < 64; off <<= 1) {
    int y = __shfl_up(x, off);
    if (lane >= off) x += y;
  }
  if (lane == 63) wsum[w] = x;
  __syncthreads();
  {
    int wo = 0;
    for (int i = 0; i < w; ++i) wo += wsum[i];
    lscan[t] = x - v + wo;
  }
  __syncthreads();

  // reserve global space per bucket
  if (t < NBUK) gbase[t] = t * BCAP + atomicAdd(&bcnt[t], lcnt[t]);
  __syncthreads();

  // place into LDS staging ordered by bucket
#pragma unroll
  for (int k = 0; k < 8; ++k) {
    if (bk[k] >= 0) {
      int p = lscan[bk[k]] + rk[k];
      stag[p] = m[k];
      dest[p] = gbase[bk[k]] + rk[k];
    }
  }
  __syncthreads();

  // coalesced copy-out (runs of same-bucket edges are contiguous)
#pragma unroll
  for (int k = 0; k < 8; ++k) {
    int p = t + k * 1024;
    if (p < here) bedge[dest[p]] = stag[p];
  }
}

// ---------------- phase B: per-bucket counting sort by dst (in-place) ----------------
// Emits rptr/rcnt/dinv. Proven round-8 geometry: 782 x 512 x 24 KB.

__global__ __launch_bounds__(512) void k_sort(const int* __restrict__ bcnt,
                                              u32* __restrict__ bedge,
                                              int* __restrict__ rptr,
                                              int* __restrict__ rcnt,
                                              float* __restrict__ dinv, int N) {
  __shared__ u32 stag[BCAP];     // 22 KB
  __shared__ int hist[BNODES];
  __shared__ int cur[BNODES];
  __shared__ int wsum2[2];
  int b = blockIdx.x, t = threadIdx.x;
  if (t < BNODES) hist[t] = 0;
  __syncthreads();
  int n = bcnt[b]; if (n > BCAP) n = BCAP;
  u32* be = bedge + (size_t)b * BCAP;

  for (int i = t; i < n; i += 512) atomicAdd(&hist[be[i] >> 20], 1);
  __syncthreads();

  // exclusive scan of hist[0..127] by threads 0..127 (2 waves)
  int lane = t & 63, w = t >> 6;
  int v = 0, x = 0;
  if (t < BNODES) { v = hist[t]; x = v; }
#pragma unroll
  for (int off = 1; off < 64; off <<= 1) {
    int y = __shfl_up(x, off);
    if (lane >= off) x += y;
  }
  if (t < BNODES && lane == 63) wsum2[w] = x;
  __syncthreads();
  if (t < BNODES) {
    int wo = (w == 1) ? wsum2[0] : 0;
    int ex = x - v + wo;
    cur[t] = ex;
    int node = (b << BSHIFT) + t;
    if (node < N) {
      rptr[node] = b * BCAP + ex;
      rcnt[node] = v;
      dinv[node] = rsqrtf((float)(v + 1));  // +1 self-loop
    }
  }
  __syncthreads();

  // rank + scatter into LDS (sorted by dloc)
  for (int i = t; i < n; i += 512) {
    u32 m = be[i];
    int p = atomicAdd(&cur[m >> 20], 1);
    stag[p] = m;
  }
  __syncthreads();

  // in-place coalesced writeback
  for (int i = t; i < n; i += 512) be[i] = stag[i];
}

// ---------------- gemm1 (MFMA 16x16x32 bf16), wave = 16 rows x ALL 64 cols ----------------
// h'[row] = dinv[row] * (x@W1)[row]. Proven form.

__global__ __launch_bounds__(256, 1) void k_gemm1(const float* __restrict__ x,
                                                  const u16* __restrict__ w1t,
                                                  const float* __restrict__ dinv,
                                                  u16* __restrict__ h1, int N) {
  int lane = threadIdx.x & 63;
  int wave = threadIdx.x >> 6;
  int rowbase = (blockIdx.x * 4 + wave) * 16;
  if (rowbase >= N) return;  // N % 16 == 0: tiles never straddle
  int mn = lane & 15, quad = lane >> 4;
  const float* arow = x + (size_t)(rowbase + mn) * IN_CH + quad * 8;

  // hoist all 16 A loads (64 VGPR) -> one vmcnt wait
  float4 a[16];
#pragma unroll
  for (int kc = 0; kc < 8; ++kc) {
    a[2 * kc] = *(const float4*)(arow + kc * 32);
    a[2 * kc + 1] = *(const float4*)(arow + kc * 32 + 4);
  }
  // convert once to bf16 frags (32 VGPR)
  u16x8 au[8];
#pragma unroll
  for (int kc = 0; kc < 8; ++kc) {
    float4 a0 = a[2 * kc], a1 = a[2 * kc + 1];
    au[kc][0] = f2bf(a0.x); au[kc][1] = f2bf(a0.y);
    au[kc][2] = f2bf(a0.z); au[kc][3] = f2bf(a0.w);
    au[kc][4] = f2bf(a1.x); au[kc][5] = f2bf(a1.y);
    au[kc][6] = f2bf(a1.z); au[kc][7] = f2bf(a1.w);
  }

  f32x4 acc[4] = {{0.f, 0.f, 0.f, 0.f}, {0.f, 0.f, 0.f, 0.f},
                  {0.f, 0.f, 0.f, 0.f}, {0.f, 0.f, 0.f, 0.f}};
#pragma unroll
  for (int c = 0; c < 4; ++c) {
    const u16* brow = w1t + (c * 16 + mn) * IN_CH + quad * 8;
    u16x8 bu[8];  // clustered, L1-hot (B is 32 KB shared chip-wide)
#pragma unroll
    for (int kc = 0; kc < 8; ++kc) bu[kc] = *(const u16x8*)(brow + kc * 32);
#pragma unroll
    for (int kc = 0; kc < 8; ++kc)
      acc[c] = __builtin_amdgcn_mfma_f32_16x16x32_bf16(
          __builtin_bit_cast(bf16x8, au[kc]), __builtin_bit_cast(bf16x8, bu[kc]),
          acc[c], 0, 0, 0);
  }
#pragma unroll
  for (int r = 0; r < 4; ++r) {
    int row = rowbase + quad * 4 + r;
    float dv = dinv[row];
#pragma unroll
    for (int c = 0; c < 4; ++c)
      h1[(size_t)row * HID + c * 16 + mn] = f2bf(dv * acc[c][r]);
  }
}

// ---------------- agg pass 1: wave per node, proven gather loop ----------------
// u[i] = dinv_i * relu( dinv_i * (sum_e h'[src_e] + h'[i]) + b1 )

__global__ __launch_bounds__(256, 4) void k_agg1(const u16* __restrict__ hin,
                                                 const int* __restrict__ rptr,
                                                 const int* __restrict__ rcnt,
                                                 const u32* __restrict__ sedge,
                                                 const float* __restrict__ bias,
                                                 u16* __restrict__ outu, int N) {
  int wid = blockIdx.x * 4 + (threadIdx.x >> 6);
  int lane = threadIdx.x & 63;
  if (wid >= N) return;
  int start = __builtin_amdgcn_readfirstlane(rptr[wid]);
  int len = __builtin_amdgcn_readfirstlane(rcnt[wid]);
  float di = rsqrtf((float)(len + 1));
  float a0 = bf2f(hin[(size_t)wid * HID + lane]);  // self-loop
  float a1 = 0.f, a2 = 0.f, a3 = 0.f;
  const u32* se = sedge + start;
  int j = 0;
  for (; j + 16 <= len; j += 16) {
    u16 v[16];
#pragma unroll
    for (int k = 0; k < 16; ++k) {
      int e = (int)(se[j + k] & 0xFFFFF);  // wave-uniform -> s_load batch
      v[k] = hin[(size_t)e * HID + lane];  // 16 gathers in flight
    }
#pragma unroll
    for (int k = 0; k < 16; ++k) {
      float f = bf2f(v[k]);
      if ((k & 3) == 0) a0 += f;
      else if ((k & 3) == 1) a1 += f;
      else if ((k & 3) == 2) a2 += f;
      else a3 += f;
    }
  }
  if (j + 8 <= len) {
    u16 v[8];
#pragma unroll
    for (int k = 0; k < 8; ++k) {
      int e = (int)(se[j + k] & 0xFFFFF);
      v[k] = hin[(size_t)e * HID + lane];
    }
#pragma unroll
    for (int k = 0; k < 8; ++k) {
      float f = bf2f(v[k]);
      if ((k & 3) == 0) a0 += f;
      else if ((k & 3) == 1) a1 += f;
      else if ((k & 3) == 2) a2 += f;
      else a3 += f;
    }
    j += 8;
  }
  if (j + 4 <= len) {
    u16 v[4];
#pragma unroll
    for (int k = 0; k < 4; ++k) {
      int e = (int)(se[j + k] & 0xFFFFF);
      v[k] = hin[(size_t)e * HID + lane];
    }
    a0 += bf2f(v[0]); a1 += bf2f(v[1]); a2 += bf2f(v[2]); a3 += bf2f(v[3]);
    j += 4;
  }
  for (; j < len; ++j) {
    int e = (int)(se[j] & 0xFFFFF);
    a0 += bf2f(hin[(size_t)e * HID + lane]);
  }
  float acc = (a0 + a1) + (a2 + a3);
  acc = fmaxf(di * acc + bias[lane], 0.f);   // relu
  outu[(size_t)wid * HID + lane] = f2bf(di * acc);  // pre-scaled u row
}

// ---------------- agg pass 2 + fused @W2, register-resident epilogue ----------------
// out[i] = dinv_i * ((sum_e u[src_e] + u[i]) @ W2) + b2
// Round-10 diagnosis: the LDS epilogue cost +22us/pass (16-KB fp32 W2 fill +
// barrier + 128 ds_read/lane dot). This version is LDS-free: each lane holds
// its W2 column in 32 VGPR (8x u16x8 from bf16 w2t, 128 B contiguous, L1-hot
// across waves/blocks); the dot uses v_readlane with compile-time lane index
// (fully unrolled) -> pure VALU, no barrier, waves fully independent.

__global__ __launch_bounds__(256, 4) void k_agg2(const u16* __restrict__ u1,
                                                 const int* __restrict__ rptr,
                                                 const int* __restrict__ rcnt,
                                                 const u32* __restrict__ sedge,
                                                 const u16* __restrict__ w2t,
                                                 const float* __restrict__ b2,
                                                 float* __restrict__ out, int N) {
  int wave = threadIdx.x >> 6, lane = threadIdx.x & 63;
  int wid = blockIdx.x * 4 + wave;   // N % 4 == 0: never out of range
  // lane's W2 column: w2t[lane][0..63], 128 B contiguous (32 VGPR)
  u16x8 wc[8];
#pragma unroll
  for (int i = 0; i < 8; ++i) wc[i] = *(const u16x8*)(w2t + lane * HID + i * 8);
  int start = __builtin_amdgcn_readfirstlane(rptr[wid]);
  int len = __builtin_amdgcn_readfirstlane(rcnt[wid]);
  float di = rsqrtf((float)(len + 1));
  float a0 = bf2f(u1[(size_t)wid * HID + lane]);  // self-loop u row
  float a1 = 0.f, a2 = 0.f, a3 = 0.f;
  const u32* se = sedge + start;
  int j = 0;
  for (; j + 16 <= len; j += 16) {
    u16 v[16];
#pragma unroll
    for (int k = 0; k < 16; ++k) {
      int e = (int)(se[j + k] & 0xFFFFF);
      v[k] = u1[(size_t)e * HID + lane];
    }
#pragma unroll
    for (int k = 0; k < 16; ++k) {
      float f = bf2f(v[k]);
      if ((k & 3) == 0) a0 += f;
      else if ((k & 3) == 1) a1 += f;
      else if ((k & 3) == 2) a2 += f;
      else a3 += f;
    }
  }
  if (j + 8 <= len) {
    u16 v[8];
#pragma unroll
    for (int k = 0; k < 8; ++k) {
      int e = (int)(se[j + k] & 0xFFFFF);
      v[k] = u1[(size_t)e * HID + lane];
    }
#pragma unroll
    for (int k = 0; k < 8; ++k) {
      float f = bf2f(v[k]);
      if ((k & 3) == 0) a0 += f;
      else if ((k & 3) == 1) a1 += f;
      else if ((k & 3) == 2) a2 += f;
      else a3 += f;
    }
    j += 8;
  }
  if (j + 4 <= len) {
    u16 v[4];
#pragma unroll
    for (int k = 0; k < 4; ++k) {
      int e = (int)(se[j + k] & 0xFFFFF);
      v[k] = u1[(size_t)e * HID + lane];
    }
    a0 += bf2f(v[0]); a1 += bf2f(v[1]); a2 += bf2f(v[2]); a3 += bf2f(v[3]);
    j += 4;
  }
  for (; j < len; ++j) {
    int e = (int)(se[j] & 0xFFFFF);
    a0 += bf2f(u1[(size_t)e * HID + lane]);
  }
  float acc = (a0 + a1) + (a2 + a3);

  // fused @W2: o[lane] = sum_k acc@laneK * W2[k][lane]; readlane(const idx) -> SGPR
  int accb = __builtin_bit_cast(int, acc);
  float o = 0.f;
#pragma unroll
  for (int k = 0; k < HID; ++k) {
    float rv = __builtin_bit_cast(float, __builtin_amdgcn_readlane(accb, k));
    o = fmaf(rv, bf2f(wc[k >> 3][k & 7]), o);
  }
  out[(size_t)wid * HID + lane] = di * o + b2[lane];
}

// ---------------- host ----------------

extern "C" void kernel_launch(void* const* d_in, const int* in_sizes, int n_in,
                              void* d_out, int out_size, void* d_ws, size_t ws_size,
                              hipStream_t stream) {
  const float* x = (const float*)d_in[0];
  const int* ei = (const int*)d_in[1];  // [2][E] int32
  const float* W1 = (const float*)d_in[2];
  const float* b1 = (const float*)d_in[3];
  const float* W2 = (const float*)d_in[4];
  const float* b2 = (const float*)d_in[5];
  float* out = (float*)d_out;

  const int N = in_sizes[0] / IN_CH;  // 100000
  const int E = in_sizes[1] / 2;      // 3200000
  const int* e_src = ei;
  const int* e_dst = ei + E;

  size_t off = 0;
  auto carve = [&](size_t bytes) -> char* {
    char* p = (char*)d_ws + off;
    off += (bytes + 255) & ~(size_t)255;
    return p;
  };
  int* bcnt = (int*)carve((size_t)NBUK * 4);
  u32* bedge = (u32*)carve((size_t)NBUK * BCAP * 4);  // 17.6 MB
  int* rptr = (int*)carve((size_t)N * 4);
  int* rcnt = (int*)carve((size_t)N * 4);
  float* dinv = (float*)carve((size_t)N * 4);
  u16* w1t = (u16*)carve(64 * 256 * 2);
  u16* w2t = (u16*)carve(64 * 64 * 2);
  u16* h1 = (u16*)carve((size_t)N * HID * 2);
  u16* u1 = (u16*)carve((size_t)N * HID * 2);

  const int n_tiles = (E + TILE - 1) / TILE;  // 391
  const int nb_g1 = (N + 63) / 64;            // 64 rows per block (4 waves x 16)

  k_wprep<<<(64 * 256 + 64 * 64 + 255) / 256, 256, 0, stream>>>(W1, W2, w1t, w2t, bcnt);
  k_part<<<n_tiles, 1024, 0, stream>>>(e_src, e_dst, bcnt, bedge, E);
  k_sort<<<NBUK, 512, 0, stream>>>(bcnt, bedge, rptr, rcnt, dinv, N);
  k_gemm1<<<nb_g1, 256, 0, stream>>>(x, w1t, dinv, h1, N);
  k_agg1<<<N / 4, 256, 0, stream>>>(h1, rptr, rcnt, bedge, b1, u1, N);
  k_agg2<<<N / 4, 256, 0, stream>>>(u1, rptr, rcnt, bedge, w2t, b2, out, N);
}

// Round 13
// 344.704 us; speedup vs baseline: 1.1290x; 1.1290x over previous
//
#include <hip/hip_runtime.h>

typedef unsigned short u16;
typedef unsigned int u32;
typedef __bf16 bf16x8 __attribute__((ext_vector_type(8)));
typedef float f32x4 __attribute__((ext_vector_type(4)));
typedef u16 u16x8 __attribute__((ext_vector_type(8)));

#define IN_CH 256
#define HID 64
#define BSHIFT 7            // 128 nodes per bucket
#define BNODES 128
#define NBUK 782            // ceil(100000 / 128)
#define BCAP 5632           // mean 4092 edges/bucket; +24 sigma headroom
#define TILE 8192           // edges per partition tile

__device__ __forceinline__ u16 f2bf(float f) {
  union { float f; unsigned u; } v; v.f = f;
  unsigned r = v.u + 0x7FFFu + ((v.u >> 16) & 1u);  // RNE
  return (u16)(r >> 16);
}
__device__ __forceinline__ float bf2f(u16 h) {
  union { unsigned u; float f; } v; v.u = ((unsigned)h) << 16;
  return v.f;
}

// W1 + W2 transpose to bf16 [n][k] layouts, AND zero bcnt (absorbed memset
// dispatch; ~10-12 us kernel+drain saved).
__global__ void k_wprep(const float* __restrict__ W1, const float* __restrict__ W2,
                        u16* __restrict__ w1t, u16* __restrict__ w2t,
                        int* __restrict__ bcnt) {
  int t = blockIdx.x * blockDim.x + threadIdx.x;
  if (t < 64 * 256) {
    int n = t >> 8, k = t & 255;
    w1t[t] = f2bf(W1[k * 64 + n]);
  }
  int t2 = t - 64 * 256;
  if (t2 >= 0 && t2 < 64 * 64) {
    int n = t2 >> 6, k = t2 & 63;
    w2t[t2] = f2bf(W2[k * 64 + n]);
  }
  if (t < NBUK) bcnt[t] = 0;
}

// ---------------- phase A: LDS-staged bucket partition (128-node buckets) ----------------
// Edge packed as u32: src (bits 0-19) | dloc (bits 20-26). Proven (round 8).

__global__ __launch_bounds__(1024) void k_part(const int* __restrict__ e_src,
                                               const int* __restrict__ e_dst,
                                               int* __restrict__ bcnt,
                                               u32* __restrict__ bedge, int E) {
  __shared__ int lcnt[1024];
  __shared__ int lscan[1024];
  __shared__ int gbase[1024];
  __shared__ int wsum[16];
  __shared__ u32 stag[TILE];
  __shared__ int dest[TILE];
  int t = threadIdx.x;
  int base = blockIdx.x * TILE;
  int here = E - base; if (here > TILE) here = TILE;

  lcnt[t] = 0;
  __syncthreads();

  u32 m[8]; int bk[8]; int rk[8];
#pragma unroll
  for (int k = 0; k < 8; ++k) {
    int e = base + t + k * 1024;
    if (e < E) {
      int s = e_src[e], d = e_dst[e];
      bk[k] = d >> BSHIFT;
      m[k] = (u32)s | ((u32)(d & (BNODES - 1)) << 20);
      rk[k] = atomicAdd(&lcnt[bk[k]], 1);
    } else bk[k] = -1;
  }
  __syncthreads();

  // exclusive scan of lcnt[0..1023] (16 waves)
  int lane = t & 63, w = t >> 6;
  int v = lcnt[t], x = v;
#pragma unroll
  for (int off = 1; off < 64; off <<= 1) {
    int y = __shfl_up(x, off);
    if (lane >= off) x += y;
  }
  if (lane == 63) wsum[w] = x;
  __syncthreads();
  {
    int wo = 0;
    for (int i = 0; i < w; ++i) wo += wsum[i];
    lscan[t] = x - v + wo;
  }
  __syncthreads();

  // reserve global space per bucket
  if (t < NBUK) gbase[t] = t * BCAP + atomicAdd(&bcnt[t], lcnt[t]);
  __syncthreads();

  // place into LDS staging ordered by bucket
#pragma unroll
  for (int k = 0; k < 8; ++k) {
    if (bk[k] >= 0) {
      int p = lscan[bk[k]] + rk[k];
      stag[p] = m[k];
      dest[p] = gbase[bk[k]] + rk[k];
    }
  }
  __syncthreads();

  // coalesced copy-out (runs of same-bucket edges are contiguous)
#pragma unroll
  for (int k = 0; k < 8; ++k) {
    int p = t + k * 1024;
    if (p < here) bedge[dest[p]] = stag[p];
  }
}

// ---------------- phase B: per-bucket counting sort by dst (in-place) ----------------
// Emits rptr/rcnt/dinv. Proven round-8 geometry: 782 x 512 x 24 KB.

__global__ __launch_bounds__(512) void k_sort(const int* __restrict__ bcnt,
                                              u32* __restrict__ bedge,
                                              int* __restrict__ rptr,
                                              int* __restrict__ rcnt,
                                              float* __restrict__ dinv, int N) {
  __shared__ u32 stag[BCAP];     // 22 KB
  __shared__ int hist[BNODES];
  __shared__ int cur[BNODES];
  __shared__ int wsum2[2];
  int b = blockIdx.x, t = threadIdx.x;
  if (t < BNODES) hist[t] = 0;
  __syncthreads();
  int n = bcnt[b]; if (n > BCAP) n = BCAP;
  u32* be = bedge + (size_t)b * BCAP;

  for (int i = t; i < n; i += 512) atomicAdd(&hist[be[i] >> 20], 1);
  __syncthreads();

  // exclusive scan of hist[0..127] by threads 0..127 (2 waves)
  int lane = t & 63, w = t >> 6;
  int v = 0, x = 0;
  if (t < BNODES) { v = hist[t]; x = v; }
#pragma unroll
  for (int off = 1; off < 64; off <<= 1) {
    int y = __shfl_up(x, off);
    if (lane >= off) x += y;
  }
  if (t < BNODES && lane == 63) wsum2[w] = x;
  __syncthreads();
  if (t < BNODES) {
    int wo = (w == 1) ? wsum2[0] : 0;
    int ex = x - v + wo;
    cur[t] = ex;
    int node = (b << BSHIFT) + t;
    if (node < N) {
      rptr[node] = b * BCAP + ex;
      rcnt[node] = v;
      dinv[node] = rsqrtf((float)(v + 1));  // +1 self-loop
    }
  }
  __syncthreads();

  // rank + scatter into LDS (sorted by dloc)
  for (int i = t; i < n; i += 512) {
    u32 m = be[i];
    int p = atomicAdd(&cur[m >> 20], 1);
    stag[p] = m;
  }
  __syncthreads();

  // in-place coalesced writeback
  for (int i = t; i < n; i += 512) be[i] = stag[i];
}

// ---------------- gemm1 (MFMA 16x16x32 bf16), wave = 16 rows x ALL 64 cols ----------------
// h'[row] = dinv[row] * (x@W1)[row]. Proven form.

__global__ __launch_bounds__(256, 1) void k_gemm1(const float* __restrict__ x,
                                                  const u16* __restrict__ w1t,
                                                  const float* __restrict__ dinv,
                                                  u16* __restrict__ h1, int N) {
  int lane = threadIdx.x & 63;
  int wave = threadIdx.x >> 6;
  int rowbase = (blockIdx.x * 4 + wave) * 16;
  if (rowbase >= N) return;  // N % 16 == 0: tiles never straddle
  int mn = lane & 15, quad = lane >> 4;
  const float* arow = x + (size_t)(rowbase + mn) * IN_CH + quad * 8;

  // hoist all 16 A loads (64 VGPR) -> one vmcnt wait
  float4 a[16];
#pragma unroll
  for (int kc = 0; kc < 8; ++kc) {
    a[2 * kc] = *(const float4*)(arow + kc * 32);
    a[2 * kc + 1] = *(const float4*)(arow + kc * 32 + 4);
  }
  // convert once to bf16 frags (32 VGPR)
  u16x8 au[8];
#pragma unroll
  for (int kc = 0; kc < 8; ++kc) {
    float4 a0 = a[2 * kc], a1 = a[2 * kc + 1];
    au[kc][0] = f2bf(a0.x); au[kc][1] = f2bf(a0.y);
    au[kc][2] = f2bf(a0.z); au[kc][3] = f2bf(a0.w);
    au[kc][4] = f2bf(a1.x); au[kc][5] = f2bf(a1.y);
    au[kc][6] = f2bf(a1.z); au[kc][7] = f2bf(a1.w);
  }

  f32x4 acc[4] = {{0.f, 0.f, 0.f, 0.f}, {0.f, 0.f, 0.f, 0.f},
                  {0.f, 0.f, 0.f, 0.f}, {0.f, 0.f, 0.f, 0.f}};
#pragma unroll
  for (int c = 0; c < 4; ++c) {
    const u16* brow = w1t + (c * 16 + mn) * IN_CH + quad * 8;
    u16x8 bu[8];  // clustered, L1-hot (B is 32 KB shared chip-wide)
#pragma unroll
    for (int kc = 0; kc < 8; ++kc) bu[kc] = *(const u16x8*)(brow + kc * 32);
#pragma unroll
    for (int kc = 0; kc < 8; ++kc)
      acc[c] = __builtin_amdgcn_mfma_f32_16x16x32_bf16(
          __builtin_bit_cast(bf16x8, au[kc]), __builtin_bit_cast(bf16x8, bu[kc]),
          acc[c], 0, 0, 0);
  }
#pragma unroll
  for (int r = 0; r < 4; ++r) {
    int row = rowbase + quad * 4 + r;
    float dv = dinv[row];
#pragma unroll
    for (int c = 0; c < 4; ++c)
      h1[(size_t)row * HID + c * 16 + mn] = f2bf(dv * acc[c][r]);
  }
}

__global__ __launch_bounds__(256) void k_gemm2(const u16* __restrict__ g1,
                                               const u16* __restrict__ w2t,
                                               const float* __restrict__ dinv,
                                               u16* __restrict__ h2) {
  int lane = threadIdx.x & 63;
  int wave = threadIdx.x >> 6;
  int rowbase = blockIdx.x * 16;
  int colbase = wave * 16;
  int mn = lane & 15, quad = lane >> 4;
  const u16* arow = g1 + (size_t)(rowbase + mn) * HID + quad * 8;
  const u16* brow = w2t + (colbase + mn) * HID + quad * 8;
  u16x8 au0 = *(const u16x8*)(arow);
  u16x8 au1 = *(const u16x8*)(arow + 32);
  u16x8 bu0 = *(const u16x8*)(brow);
  u16x8 bu1 = *(const u16x8*)(brow + 32);
  f32x4 acc = {0.f, 0.f, 0.f, 0.f};
  acc = __builtin_amdgcn_mfma_f32_16x16x32_bf16(
      __builtin_bit_cast(bf16x8, au0), __builtin_bit_cast(bf16x8, bu0), acc, 0, 0, 0);
  acc = __builtin_amdgcn_mfma_f32_16x16x32_bf16(
      __builtin_bit_cast(bf16x8, au1), __builtin_bit_cast(bf16x8, bu1), acc, 0, 0, 0);
#pragma unroll
  for (int r = 0; r < 4; ++r) {
    int row = rowbase + quad * 4 + r;
    h2[(size_t)row * HID + colbase + mn] = f2bf(dinv[row] * acc[r]);
  }
}

// ---------------- aggregation: wave per node, scalar edges, multi-accumulator ----------------
// out[i] = dinv_i * (sum_e h'[src_e] + h'[i]) + bias
// The proven ~58-64us/pass form. Three independent implementations (scalar 2-B,
// vector 8-B, LDS-accumulator) all hit the same L2-miss/L3 ~2.8-TB/s floor:
// this is the transaction-bound minimum for random 128-B row gathers.

template <bool RELU, bool BF16OUT>
__global__ __launch_bounds__(256, 4) void k_agg(const u16* __restrict__ hin,
                                                const int* __restrict__ rptr,
                                                const int* __restrict__ rcnt,
                                                const u32* __restrict__ sedge,
                                                const float* __restrict__ bias,
                                                void* __restrict__ outv, int N) {
  int wid = blockIdx.x * 4 + (threadIdx.x >> 6);
  int lane = threadIdx.x & 63;
  if (wid >= N) return;
  int start = __builtin_amdgcn_readfirstlane(rptr[wid]);
  int len = __builtin_amdgcn_readfirstlane(rcnt[wid]);
  float di = rsqrtf((float)(len + 1));
  float a0 = bf2f(hin[(size_t)wid * HID + lane]);  // self-loop
  float a1 = 0.f, a2 = 0.f, a3 = 0.f;
  const u32* se = sedge + start;
  int j = 0;
  for (; j + 16 <= len; j += 16) {
    u16 v[16];
#pragma unroll
    for (int k = 0; k < 16; ++k) {
      int e = (int)(se[j + k] & 0xFFFFF);  // wave-uniform -> s_load batch
      v[k] = hin[(size_t)e * HID + lane];  // 16 gathers in flight
    }
#pragma unroll
    for (int k = 0; k < 16; ++k) {
      float f = bf2f(v[k]);
      if ((k & 3) == 0) a0 += f;
      else if ((k & 3) == 1) a1 += f;
      else if ((k & 3) == 2) a2 += f;
      else a3 += f;
    }
  }
  if (j + 8 <= len) {
    u16 v[8];
#pragma unroll
    for (int k = 0; k < 8; ++k) {
      int e = (int)(se[j + k] & 0xFFFFF);
      v[k] = hin[(size_t)e * HID + lane];
    }
#pragma unroll
    for (int k = 0; k < 8; ++k) {
      float f = bf2f(v[k]);
      if ((k & 3) == 0) a0 += f;
      else if ((k & 3) == 1) a1 += f;
      else if ((k & 3) == 2) a2 += f;
      else a3 += f;
    }
    j += 8;
  }
  if (j + 4 <= len) {
    u16 v[4];
#pragma unroll
    for (int k = 0; k < 4; ++k) {
      int e = (int)(se[j + k] & 0xFFFFF);
      v[k] = hin[(size_t)e * HID + lane];
    }
    a0 += bf2f(v[0]); a1 += bf2f(v[1]); a2 += bf2f(v[2]); a3 += bf2f(v[3]);
    j += 4;
  }
  for (; j < len; ++j) {
    int e = (int)(se[j] & 0xFFFFF);
    a0 += bf2f(hin[(size_t)e * HID + lane]);
  }
  float acc = (a0 + a1) + (a2 + a3);
  acc = di * acc + bias[lane];
  if (RELU) acc = fmaxf(acc, 0.f);
  if (BF16OUT) ((u16*)outv)[(size_t)wid * HID + lane] = f2bf(acc);
  else ((float*)outv)[(size_t)wid * HID + lane] = acc;
}

// ---------------- host ----------------

extern "C" void kernel_launch(void* const* d_in, const int* in_sizes, int n_in,
                              void* d_out, int out_size, void* d_ws, size_t ws_size,
                              hipStream_t stream) {
  const float* x = (const float*)d_in[0];
  const int* ei = (const int*)d_in[1];  // [2][E] int32
  const float* W1 = (const float*)d_in[2];
  const float* b1 = (const float*)d_in[3];
  const float* W2 = (const float*)d_in[4];
  const float* b2 = (const float*)d_in[5];
  float* out = (float*)d_out;

  const int N = in_sizes[0] / IN_CH;  // 100000
  const int E = in_sizes[1] / 2;      // 3200000
  const int* e_src = ei;
  const int* e_dst = ei + E;

  size_t off = 0;
  auto carve = [&](size_t bytes) -> char* {
    char* p = (char*)d_ws + off;
    off += (bytes + 255) & ~(size_t)255;
    return p;
  };
  int* bcnt = (int*)carve((size_t)NBUK * 4);
  u32* bedge = (u32*)carve((size_t)NBUK * BCAP * 4);  // 17.6 MB
  int* rptr = (int*)carve((size_t)N * 4);
  int* rcnt = (int*)carve((size_t)N * 4);
  float* dinv = (float*)carve((size_t)N * 4);
  u16* w1t = (u16*)carve(64 * 256 * 2);
  u16* w2t = (u16*)carve(64 * 64 * 2);
  u16* h1 = (u16*)carve((size_t)N * HID * 2);  // reused for h2
  u16* g1 = (u16*)carve((size_t)N * HID * 2);

  const int n_tiles = (E + TILE - 1) / TILE;  // 391
  const int nb_g1 = (N + 63) / 64;            // 64 rows per block (4 waves x 16)

  k_wprep<<<(64 * 256 + 64 * 64 + 255) / 256, 256, 0, stream>>>(W1, W2, w1t, w2t, bcnt);
  k_part<<<n_tiles, 1024, 0, stream>>>(e_src, e_dst, bcnt, bedge, E);
  k_sort<<<NBUK, 512, 0, stream>>>(bcnt, bedge, rptr, rcnt, dinv, N);
  k_gemm1<<<nb_g1, 256, 0, stream>>>(x, w1t, dinv, h1, N);
  k_agg<true, true><<<(N + 3) / 4, 256, 0, stream>>>(h1, rptr, rcnt, bedge, b1, g1, N);
  k_gemm2<<<N / 16, 256, 0, stream>>>(g1, w2t, dinv, h1);
  k_agg<false, false><<<(N + 3) / 4, 256, 0, stream>>>(h1, rptr, rcnt, bedge, b2, out, N);
}